// Round 17
// baseline (548.365 us; speedup 1.0000x reference)
//
#include <hip/hip_runtime.h>

#define N 512
#define L 8192

#define LOG_MIN -6.907755278982137f
#define LOG_MAX -2.302585092994046f

typedef __attribute__((ext_vector_type(8))) short short8;
typedef __attribute__((ext_vector_type(4))) float f4;
typedef __attribute__((ext_vector_type(4))) unsigned u4;

__device__ __forceinline__ float get_delta(const float* logd) {
  float ld = logd[0];
  ld = fminf(fmaxf(ld, LOG_MIN), LOG_MAX);
  return expf(ld);
}
__device__ __forceinline__ unsigned short f2bf(float x) {
  union { float f; unsigned int u; } c; c.f = x;
  unsigned int u = c.u;
  u += 0x7FFFu + ((u >> 16) & 1u);
  return (unsigned short)(u >> 16);
}
__device__ __forceinline__ unsigned int pack2(unsigned short a, unsigned short b) {
  return (unsigned int)a | ((unsigned int)b << 16);
}
__device__ __forceinline__ void wts4(float* p, f4 v) { *(f4*)p = v; }
__device__ __forceinline__ void wts4u(unsigned* p, u4 v) { *(u4*)p = v; }
#define PIN(x) asm volatile("" : "+v"(x))

// ---------------------------------------------------------------------------
// ws layout (floats):
//   0 kvec (8192) | 8192 Vtr (128*512) | 73728 W (64*512) | 106496 Xi (512*512)
//   368640 U2 (2*128*128) | 401408 U3 (256*256)
//   466944 PB[12] (12*512*512)
//   3612672 Atab (1MB) | 3874816 Btab (512KB)
// NOTE: sq/wstep issue unconditional 16-tile loads; over-reads past a PB
// buffer land in the NEXT ws buffer (allocated, read-only garbage) and are
// masked out of all live outputs by the block-uniform compute guards.
// ---------------------------------------------------------------------------

__device__ void diag64(const float* __restrict__ A, float h,
                       float* __restrict__ Xi, int blk, int tid, float* sm) {
  float* Ash = sm;          // [64][65]
  float* xs  = sm + 4160;   // [64][65]
  float* dinv = sm + 8320;  // [64]
  int i0 = blk * 64;
  int r = tid >> 2, c0 = (tid & 3) * 16;
#pragma unroll
  for (int q = 0; q < 16; q += 4) {
    f4 v = *(const f4*)(A + (size_t)(i0 + r) * N + i0 + c0 + q);
    Ash[r * 65 + c0 + q] = v.x; Ash[r * 65 + c0 + q + 1] = v.y;
    Ash[r * 65 + c0 + q + 2] = v.z; Ash[r * 65 + c0 + q + 3] = v.w;
  }
  for (int i = tid; i < 4160; i += 256) xs[i] = 0.f;
  __syncthreads();
  if (tid < 64) dinv[tid] = 1.f / (1.f - h * Ash[tid * 65 + tid]);
  __syncthreads();
  int t = tid >> 2, sub = tid & 3;
  for (int rr = 0; rr < 64; ++rr) {
    if (t <= rr) {
      float s = 0.f;
      for (int k = t + sub; k < rr; k += 4) s += Ash[rr * 65 + k] * xs[k * 65 + t];
      s += __shfl_xor(s, 1, 64);
      s += __shfl_xor(s, 2, 64);
      if (sub == 0)
        xs[rr * 65 + t] = (((rr == t) ? 1.f : 0.f) + h * s) * dinv[rr];
    }
  }
  __syncthreads();
#pragma unroll
  for (int q = 0; q < 16; q += 4) {
    f4 v = {xs[r * 65 + c0 + q], xs[r * 65 + c0 + q + 1],
            xs[r * 65 + c0 + q + 2], xs[r * 65 + c0 + q + 3]};
    wts4(Xi + (size_t)(i0 + r) * N + i0 + c0 + q, v);
  }
}

// All-K-upfront 32x32-tile GEMM with pinned load batch (NT = 4 or 8 only).
template <int NT>
__device__ void gemm32t(const float* __restrict__ A_, int lda,
                        const float* __restrict__ B_, int ldb,
                        float* __restrict__ C_, int ldc,
                        int bi, int bj, float alpha, int tid, float* sm) {
  float* As = sm;          // [32][33]
  float* Bs = sm + 1056;   // [32][36]
  int lr = tid >> 3, lc = (tid & 7) * 4;
  const float* ap = A_ + (size_t)(bi * 32 + lr) * lda + lc;
  const float* bp = B_ + (size_t)lr * ldb + bj * 32 + lc;
  f4 aR[NT], bR[NT];
#pragma unroll
  for (int t = 0; t < NT; ++t) {
    aR[t] = *(const f4*)(ap + 32 * t);
    bR[t] = *(const f4*)(bp + (size_t)(32 * t) * ldb);
  }
#pragma unroll
  for (int t = 0; t < NT; ++t) { PIN(aR[t]); PIN(bR[t]); }
  float acc[4] = {0.f, 0.f, 0.f, 0.f};
#pragma unroll
  for (int t = 0; t < NT; ++t) {
    As[lr * 33 + lc] = aR[t].x; As[lr * 33 + lc + 1] = aR[t].y;
    As[lr * 33 + lc + 2] = aR[t].z; As[lr * 33 + lc + 3] = aR[t].w;
    *(f4*)&Bs[lr * 36 + lc] = bR[t];
    __syncthreads();
#pragma unroll
    for (int kk = 0; kk < 32; ++kk) {
      float a = As[lr * 33 + kk];
      f4 bb = *(const f4*)&Bs[kk * 36 + lc];
      acc[0] += a * bb.x; acc[1] += a * bb.y;
      acc[2] += a * bb.z; acc[3] += a * bb.w;
    }
    __syncthreads();
  }
  f4 o = {alpha * acc[0], alpha * acc[1], alpha * acc[2], alpha * acc[3]};
  wts4(&C_[(size_t)(bi * 32 + lr) * ldc + bj * 32 + lc], o);
}

// 32x32-tile lower-tri squaring. UNCONDITIONAL 16-tile loads (over-reads are
// masked by the block-uniform t<nk compute guard); first: P := 2P - I on read.
__device__ void sq32(const float* __restrict__ P, float* __restrict__ Q,
                     int bi, int bj, int first, int tid, float* sm) {
  float* As = sm;
  float* Bs = sm + 1056;   // [32][36]
  int lr = tid >> 3, lc = (tid & 7) * 4;
  int nk = bi - bj + 1;
  int kb0 = bj * 32;
  int arow = bi * 32 + lr;
  const float* ap = P + (size_t)arow * N + lc;
  const float* bp = P + bj * 32 + lc;
  f4 aR[16], bR[16];
#pragma unroll
  for (int t = 0; t < 16; ++t) {
    int kt = kb0 + 32 * t;
    aR[t] = *(const f4*)(ap + kt);
    bR[t] = *(const f4*)(bp + (size_t)(kt + lr) * N);
  }
#pragma unroll
  for (int t = 0; t < 16; ++t) { PIN(aR[t]); PIN(bR[t]); }
  float acc[4] = {0.f, 0.f, 0.f, 0.f};
#pragma unroll
  for (int t = 0; t < 16; ++t) {
    if (t < nk) {
      int kb = kb0 + 32 * t;
      float a4[4] = {aR[t].x, aR[t].y, aR[t].z, aR[t].w};
      float b4[4] = {bR[t].x, bR[t].y, bR[t].z, bR[t].w};
      if (first) {
#pragma unroll
        for (int j = 0; j < 4; ++j) {
          a4[j] = 2.f * a4[j] - ((arow == kb + lc + j) ? 1.f : 0.f);
          b4[j] = 2.f * b4[j] - ((kb + lr == bj * 32 + lc + j) ? 1.f : 0.f);
        }
      }
      As[lr * 33 + lc] = a4[0]; As[lr * 33 + lc + 1] = a4[1];
      As[lr * 33 + lc + 2] = a4[2]; As[lr * 33 + lc + 3] = a4[3];
      f4 bv = {b4[0], b4[1], b4[2], b4[3]};
      *(f4*)&Bs[lr * 36 + lc] = bv;
      __syncthreads();
#pragma unroll
      for (int kk = 0; kk < 32; ++kk) {
        float a = As[lr * 33 + kk];
        f4 bb = *(const f4*)&Bs[kk * 36 + lc];
        acc[0] += a * bb.x; acc[1] += a * bb.y;
        acc[2] += a * bb.z; acc[3] += a * bb.w;
      }
      __syncthreads();
    }
  }
  f4 o = {acc[0], acc[1], acc[2], acc[3]};
  wts4(&Q[(size_t)(bi * 32 + lr) * N + bj * 32 + lc], o);
}

// Vtr[base+c][n] = sum_k P[n][k]*Vtr[c][k]. Unconditional loads; garbage rows
// (crow>=base / t>=nk) only reach outputs that are themselves masked.
__device__ void vstep_g(const float* __restrict__ P, float* __restrict__ Vtr,
                        int base, int first, int bi, int tid, float* sm) {
  float* As = sm;          // [32][33]
  float* Bs = sm + 1056;   // [32][33]
  int lr = tid >> 3, lc = (tid & 7) * 4;
  int cq = tid >> 3, n4 = (tid & 7) * 4;
  int nk = bi + 1;
  const float* ap = P + (size_t)(bi * 32 + lr) * N + lc;
  f4 aR[16];
#pragma unroll
  for (int t = 0; t < 16; ++t) aR[t] = *(const f4*)(ap + 32 * t);
#pragma unroll
  for (int t = 0; t < 16; ++t) PIN(aR[t]);
  int ncj = (base > 32) ? 2 : 1;
  for (int cj = 0; cj < ncj; ++cj) {
    int crow = cj * 32 + lr;
    const float* bp = Vtr + (size_t)crow * N + lc;
    f4 bR[16];
#pragma unroll
    for (int t = 0; t < 16; ++t) bR[t] = *(const f4*)(bp + 32 * t);
#pragma unroll
    for (int t = 0; t < 16; ++t) PIN(bR[t]);
    float acc[4] = {0.f, 0.f, 0.f, 0.f};
#pragma unroll
    for (int t = 0; t < 16; ++t) {
      if (t < nk) {
        int kb = 32 * t;
        float a4[4] = {aR[t].x, aR[t].y, aR[t].z, aR[t].w};
        if (first) {
#pragma unroll
          for (int j = 0; j < 4; ++j)
            a4[j] = 2.f * a4[j] - ((bi * 32 + lr == kb + lc + j) ? 1.f : 0.f);
        }
        As[lr * 33 + lc] = a4[0]; As[lr * 33 + lc + 1] = a4[1];
        As[lr * 33 + lc + 2] = a4[2]; As[lr * 33 + lc + 3] = a4[3];
        Bs[lr * 33 + lc] = bR[t].x; Bs[lr * 33 + lc + 1] = bR[t].y;
        Bs[lr * 33 + lc + 2] = bR[t].z; Bs[lr * 33 + lc + 3] = bR[t].w;
        __syncthreads();
#pragma unroll
        for (int kk = 0; kk < 32; ++kk) {
          float b = Bs[cq * 33 + kk];
          acc[0] += As[(n4 + 0) * 33 + kk] * b;
          acc[1] += As[(n4 + 1) * 33 + kk] * b;
          acc[2] += As[(n4 + 2) * 33 + kk] * b;
          acc[3] += As[(n4 + 3) * 33 + kk] * b;
        }
        __syncthreads();
      }
    }
    int c = cj * 32 + cq;
    if (c < base) {
      f4 o = {acc[0], acc[1], acc[2], acc[3]};
      wts4(&Vtr[(size_t)(base + c) * N + bi * 32 + n4], o);
    }
    if (cj + 1 < ncj) __syncthreads();
  }
}

// W[base+q][c] = sum_k W[q][k]*P[k][c], K from cj*32. Unconditional loads.
__device__ void wstep_g(const float* __restrict__ P, float* __restrict__ W,
                        int base, int cj, int tid, float* sm) {
  float* As = sm;
  float* Bs = sm + 1056;   // [32][36]
  int lr = tid >> 3, lc = (tid & 7) * 4;
  int kb0 = cj * 32, nk = 16 - cj;
  const float* ap = W + (size_t)lr * N + lc;
  const float* bp = P + cj * 32 + lc;
  f4 aR[16], bR[16];
#pragma unroll
  for (int t = 0; t < 16; ++t) {
    int kt = kb0 + 32 * t;
    aR[t] = *(const f4*)(ap + kt);
    bR[t] = *(const f4*)(bp + (size_t)(kt + lr) * N);
  }
#pragma unroll
  for (int t = 0; t < 16; ++t) { PIN(aR[t]); PIN(bR[t]); }
  float acc[4] = {0.f, 0.f, 0.f, 0.f};
#pragma unroll
  for (int t = 0; t < 16; ++t) {
    if (t < nk) {
      As[lr * 33 + lc] = aR[t].x; As[lr * 33 + lc + 1] = aR[t].y;
      As[lr * 33 + lc + 2] = aR[t].z; As[lr * 33 + lc + 3] = aR[t].w;
      *(f4*)&Bs[lr * 36 + lc] = bR[t];
      __syncthreads();
#pragma unroll
      for (int kk = 0; kk < 32; ++kk) {
        float a = As[lr * 33 + kk];
        f4 bb = *(const f4*)&Bs[kk * 36 + lc];
        acc[0] += a * bb.x; acc[1] += a * bb.y;
        acc[2] += a * bb.z; acc[3] += a * bb.w;
      }
      __syncthreads();
    }
  }
  if (lr < base) {
    f4 o = {acc[0], acc[1], acc[2], acc[3]};
    wts4(&W[(size_t)(base + lr) * N + cj * 32 + lc], o);
  }
}

// kvec[q][r] = sum_n W[q][n]*Vtr[r][n], K=512, pinned batch.
__device__ void kfinal_g(const float* __restrict__ W, const float* __restrict__ Vtr,
                         float* __restrict__ kvec, int bi, int bj, int tid, float* sm) {
  float* As = sm;
  float* Bs = sm + 1056;
  int lr = tid >> 3, lc = (tid & 7) * 4;
  int q = tid >> 3, r4 = (tid & 7) * 4;
  const float* ap = W + (size_t)(bi * 32 + lr) * N + lc;
  const float* bp = Vtr + (size_t)(bj * 32 + lr) * N + lc;
  f4 aR[16], bR[16];
#pragma unroll
  for (int t = 0; t < 16; ++t) {
    aR[t] = *(const f4*)(ap + 32 * t);
    bR[t] = *(const f4*)(bp + 32 * t);
  }
#pragma unroll
  for (int t = 0; t < 16; ++t) { PIN(aR[t]); PIN(bR[t]); }
  float acc[4] = {0.f, 0.f, 0.f, 0.f};
#pragma unroll
  for (int t = 0; t < 16; ++t) {
    As[lr * 33 + lc] = aR[t].x; As[lr * 33 + lc + 1] = aR[t].y;
    As[lr * 33 + lc + 2] = aR[t].z; As[lr * 33 + lc + 3] = aR[t].w;
    Bs[lr * 33 + lc] = bR[t].x; Bs[lr * 33 + lc + 1] = bR[t].y;
    Bs[lr * 33 + lc + 2] = bR[t].z; Bs[lr * 33 + lc + 3] = bR[t].w;
    __syncthreads();
#pragma unroll
    for (int kk = 0; kk < 32; ++kk) {
      float a = As[q * 33 + kk];
      acc[0] += a * Bs[(r4 + 0) * 33 + kk];
      acc[1] += a * Bs[(r4 + 1) * 33 + kk];
      acc[2] += a * Bs[(r4 + 2) * 33 + kk];
      acc[3] += a * Bs[(r4 + 3) * 33 + kk];
    }
    __syncthreads();
  }
  f4 o = {acc[0], acc[1], acc[2], acc[3]};
  wts4(&kvec[(size_t)(bi * 32 + q) * 128 + bj * 32 + r4], o);
}

// Vtr[0][n] = delta*(Xi*Bm)[n]: 16 blocks x 32 rows.
__device__ void bd1_body(const float* __restrict__ Xi, const float* __restrict__ Bm,
                         float delta, float* __restrict__ Vtr, int bb, int tid,
                         float* sm) {
  float* bs = sm;
  if (tid < 128) ((f4*)bs)[tid] = ((const f4*)Bm)[tid];
  __syncthreads();
  int w = tid >> 6, lane = tid & 63;
#pragma unroll
  for (int pass = 0; pass < 8; ++pass) {
    int row = bb * 32 + w * 8 + pass;
    const float* Xr = Xi + (size_t)row * N + lane * 8;
    f4 a0 = *(const f4*)Xr;
    f4 a1 = *(const f4*)(Xr + 4);
    const float* bp = bs + lane * 8;
    float acc = a0.x * bp[0] + a0.y * bp[1] + a0.z * bp[2] + a0.w * bp[3]
              + a1.x * bp[4] + a1.y * bp[5] + a1.z * bp[6] + a1.w * bp[7];
    acc += __shfl_xor(acc, 1, 64);
    acc += __shfl_xor(acc, 2, 64);
    acc += __shfl_xor(acc, 4, 64);
    acc += __shfl_xor(acc, 8, 64);
    acc += __shfl_xor(acc, 16, 64);
    acc += __shfl_xor(acc, 32, 64);
    if (lane == 0) Vtr[row] = delta * acc;
  }
}

__device__ __forceinline__ void afrag_unit(const float* __restrict__ X,
                                           unsigned* __restrict__ Atab, int u) {
  int lane = u & 63;
  int f = u >> 6;
  int bt = f >> 8, ut = f & 255;
  int row = bt * 16 + (lane & 15);
  int u0 = ut * 32 + ((lane >> 4) << 3);
  const float* xp = X + (size_t)row * L + u0;
  unsigned short v[8];
#pragma unroll
  for (int e = 0; e < 8; ++e) v[e] = f2bf(xp[e]);
  u4 o = {pack2(v[0], v[1]), pack2(v[2], v[3]), pack2(v[4], v[5]), pack2(v[6], v[7])};
  wts4u(Atab + ((size_t)f * 64 + lane) * 4, o);
}

__device__ __forceinline__ void bfrag_unit(const float* __restrict__ kvec,
                                           unsigned* __restrict__ Btab, int u) {
  int lane = u & 63;
  int si = u >> 6;
  int base = si * 16 + (lane & 15) - ((lane >> 4) << 3);
  unsigned short v[8];
#pragma unroll
  for (int e = 0; e < 8; ++e) {
    int idx = base - e;
    float x = (idx >= 0) ? kvec[idx] : 0.0f;
    v[e] = f2bf(x);
  }
  u4 o = {pack2(v[0], v[1]), pack2(v[2], v[3]), pack2(v[4], v[5]), pack2(v[6], v[7])};
  wts4u(Btab + ((size_t)si * 64 + lane) * 4, o);
}

__device__ __forceinline__ void tridec(int b, int& bi, int& bj) {
  int sbi = 0, srem = b;
  while (srem > sbi) { srem -= (sbi + 1); ++sbi; }
  bi = sbi; bj = srem;
}

// --- phase kernels ----------------------------------------------------------

__global__ __launch_bounds__(256, 1) void k_p0(const float* __restrict__ A,
                                               const float* __restrict__ C,
                                               const float* __restrict__ logd,
                                               const float* __restrict__ X,
                                               float* __restrict__ Xi,
                                               float* __restrict__ W,
                                               unsigned* __restrict__ Atab) {
  __shared__ float sm[8448];
  int b = blockIdx.x, tid = threadIdx.x;
  if (b < 8) {
    diag64(A, 0.5f * get_delta(logd), Xi, b, tid, sm);
  } else if (b < 36) {
    int idx = b - 8, bi = 0, bj = 0, cnt = 0;
    for (int i = 0; i < 8; ++i)
      for (int j = i + 1; j < 8; ++j) { if (cnt == idx) { bi = i; bj = j; } ++cnt; }
    int r = tid >> 2, c0 = (tid & 3) * 16;
    f4 z = {0.f, 0.f, 0.f, 0.f};
#pragma unroll
    for (int q = 0; q < 16; q += 4)
      wts4(Xi + (size_t)(bi * 64 + r) * N + bj * 64 + c0 + q, z);
  } else if (b == 36) {
    for (int i = tid; i < N; i += 256) W[i] = C[i];
  } else {
    for (int u = (b - 37) * 256 + tid; u < 65536; u += 115 * 256)
      afrag_unit(X, Atab, u);
  }
}

__global__ __launch_bounds__(256, 1) void k_lvl64(const float* __restrict__ A,
                                                  const float* __restrict__ logd,
                                                  float* __restrict__ Xi) {
  __shared__ float sm[8448];
  float* X11s = sm;
  float* Us = sm + 4160;
  float h = 0.5f * get_delta(logd);
  int g = blockIdx.x, tid = threadIdx.x;
  int b11 = 128 * g, b22 = 128 * g + 64;
  int r = tid >> 2, c0 = (tid & 3) * 16;
#pragma unroll
  for (int q = 0; q < 16; q += 4) {
    f4 v = *(const f4*)(Xi + (size_t)(b11 + r) * N + b11 + c0 + q);
    X11s[r * 65 + c0 + q] = v.x; X11s[r * 65 + c0 + q + 1] = v.y;
    X11s[r * 65 + c0 + q + 2] = v.z; X11s[r * 65 + c0 + q + 3] = v.w;
  }
  f4 aR[16];
#pragma unroll
  for (int t = 0; t < 16; ++t)
    aR[t] = *(const f4*)(A + (size_t)(b22 + r) * N + b11 + 4 * t);
#pragma unroll
  for (int t = 0; t < 16; ++t) PIN(aR[t]);
  __syncthreads();
  float u[16];
#pragma unroll
  for (int j = 0; j < 16; ++j) u[j] = 0.f;
#pragma unroll 4
  for (int k4 = 0; k4 < 16; ++k4) {
    float av[4] = {aR[k4].x, aR[k4].y, aR[k4].z, aR[k4].w};
#pragma unroll
    for (int s = 0; s < 4; ++s) {
      int k = 4 * k4 + s;
      float aa = av[s];
#pragma unroll
      for (int j = 0; j < 16; j += 4) {
        f4 xv = *(const f4*)&X11s[k * 65 + c0 + j];
        u[j] += aa * xv.x; u[j + 1] += aa * xv.y;
        u[j + 2] += aa * xv.z; u[j + 3] += aa * xv.w;
      }
    }
  }
  f4 xR[16];
#pragma unroll
  for (int t = 0; t < 16; ++t)
    xR[t] = *(const f4*)(Xi + (size_t)(b22 + r) * N + b22 + 4 * t);
#pragma unroll
  for (int t = 0; t < 16; ++t) PIN(xR[t]);
#pragma unroll
  for (int j = 0; j < 16; ++j) Us[r * 65 + c0 + j] = u[j];
  __syncthreads();
  float x[16];
#pragma unroll
  for (int j = 0; j < 16; ++j) x[j] = 0.f;
#pragma unroll 4
  for (int k4 = 0; k4 < 16; ++k4) {
    float av[4] = {xR[k4].x, xR[k4].y, xR[k4].z, xR[k4].w};
#pragma unroll
    for (int s = 0; s < 4; ++s) {
      int k = 4 * k4 + s;
      float aa = av[s];
#pragma unroll
      for (int j = 0; j < 16; j += 4) {
        f4 xv = *(const f4*)&Us[k * 65 + c0 + j];
        x[j] += aa * xv.x; x[j + 1] += aa * xv.y;
        x[j + 2] += aa * xv.z; x[j + 3] += aa * xv.w;
      }
    }
  }
#pragma unroll
  for (int j = 0; j < 16; j += 4) {
    f4 v = {h * x[j], h * x[j + 1], h * x[j + 2], h * x[j + 3]};
    wts4(&Xi[(size_t)(b22 + r) * N + b11 + c0 + j], v);
  }
}

__global__ __launch_bounds__(256, 1) void k_triA(const float* __restrict__ A,
                                                 const float* __restrict__ Xi,
                                                 float* __restrict__ U2) {
  __shared__ float sm[2304];
  int b = blockIdx.x, tid = threadIdx.x;
  int g = b >> 4, t = b & 15;
  gemm32t<4>(A + (size_t)(256 * g + 128) * N + 256 * g, N,
             Xi + (size_t)(256 * g) * (N + 1), N,
             U2 + g * 16384, 128, t >> 2, t & 3, 1.0f, tid, sm);
}
__global__ __launch_bounds__(256, 1) void k_triB(const float* __restrict__ logd,
                                                 float* __restrict__ Xi,
                                                 const float* __restrict__ U2) {
  __shared__ float sm[2304];
  int b = blockIdx.x, tid = threadIdx.x;
  int g = b >> 4, t = b & 15;
  float h = 0.5f * get_delta(logd);
  gemm32t<4>(Xi + (size_t)(256 * g + 128) * (N + 1), N, U2 + g * 16384, 128,
             Xi + (size_t)(256 * g + 128) * N + 256 * g, N, t >> 2, t & 3, h, tid, sm);
}
__global__ __launch_bounds__(256, 1) void k_triC(const float* __restrict__ A,
                                                 const float* __restrict__ Xi,
                                                 float* __restrict__ U3) {
  __shared__ float sm[2304];
  int b = blockIdx.x, tid = threadIdx.x;
  gemm32t<8>(A + (size_t)256 * N, N, Xi, N, U3, 256, b >> 3, b & 7, 1.0f, tid, sm);
}
__global__ __launch_bounds__(256, 1) void k_triD(const float* __restrict__ logd,
                                                 float* __restrict__ Xi,
                                                 const float* __restrict__ U3) {
  __shared__ float sm[2304];
  int b = blockIdx.x, tid = threadIdx.x;
  float h = 0.5f * get_delta(logd);
  gemm32t<8>(Xi + (size_t)256 * (N + 1), N, U3, 256,
             Xi + (size_t)256 * N, N, b >> 3, b & 7, h, tid, sm);
}

__global__ __launch_bounds__(256, 1) void k_sqbd(const float* __restrict__ Xi,
                                                 float* __restrict__ Q,
                                                 const float* __restrict__ Bm,
                                                 const float* __restrict__ logd,
                                                 float* __restrict__ Vtr) {
  __shared__ float sm[2304];
  int b = blockIdx.x, tid = threadIdx.x;
  if (b < 136) {
    int bi, bj; tridec(b, bi, bj);
    sq32(Xi, Q, bi, bj, 1, tid, sm);
  } else {
    bd1_body(Xi, Bm, get_delta(logd), Vtr, b - 136, tid, sm);
  }
}

__global__ __launch_bounds__(256, 1) void k_sqv(const float* __restrict__ P,
                                                float* __restrict__ Q,
                                                const float* __restrict__ Pv,
                                                float* __restrict__ Vtr,
                                                int base, int first) {
  __shared__ float sm[2304];
  int b = blockIdx.x, tid = threadIdx.x;
  if (b < 136) {
    int bi, bj; tridec(b, bi, bj);
    sq32(P, Q, bi, bj, 0, tid, sm);
  } else {
    vstep_g(Pv, Vtr, base, first, b - 136, tid, sm);
  }
}

__global__ __launch_bounds__(256, 1) void k_sqvw(const float* __restrict__ P,
                                                 float* __restrict__ Q,
                                                 const float* __restrict__ Pv,
                                                 float* __restrict__ Vtr,
                                                 const float* __restrict__ Pw,
                                                 float* __restrict__ W) {
  __shared__ float sm[2304];
  int b = blockIdx.x, tid = threadIdx.x;
  if (b < 136) {
    int bi, bj; tridec(b, bi, bj);
    sq32(P, Q, bi, bj, 0, tid, sm);
  } else if (b < 152) {
    vstep_g(Pv, Vtr, 64, 0, b - 136, tid, sm);
  } else {
    wstep_g(Pw, W, 1, b - 152, tid, sm);
  }
}

__global__ __launch_bounds__(256, 1) void k_sqw(const float* __restrict__ P,
                                                float* __restrict__ Q,
                                                const float* __restrict__ Pw,
                                                float* __restrict__ W,
                                                int base) {
  __shared__ float sm[2304];
  int b = blockIdx.x, tid = threadIdx.x;
  if (b < 136) {
    int bi, bj; tridec(b, bi, bj);
    sq32(P, Q, bi, bj, 0, tid, sm);
  } else {
    wstep_g(Pw, W, base, b - 136, tid, sm);
  }
}

__global__ __launch_bounds__(256, 1) void k_wf(const float* __restrict__ Pw,
                                               float* __restrict__ W, int base) {
  __shared__ float sm[2304];
  wstep_g(Pw, W, base, blockIdx.x, threadIdx.x, sm);
}

__global__ __launch_bounds__(256, 1) void k_kf(const float* __restrict__ W,
                                               const float* __restrict__ Vtr,
                                               float* __restrict__ kvec) {
  __shared__ float sm[2304];
  kfinal_g(W, Vtr, kvec, blockIdx.x >> 2, blockIdx.x & 3, threadIdx.x, sm);
}

__global__ __launch_bounds__(256, 1) void k_bf(const float* __restrict__ kvec,
                                               unsigned* __restrict__ Btab) {
  bfrag_unit(kvec, Btab, blockIdx.x * 256 + threadIdx.x);
}

// Conv: 1024 blocks x 4 waves, 2-way split-K + bt-split; LDS pair reduce.
__global__ __launch_bounds__(256, 1) void k_convmm(const short8* __restrict__ Atab,
                                                   const short8* __restrict__ Btab,
                                                   const float* __restrict__ X,
                                                   const float* __restrict__ Dp,
                                                   float* __restrict__ Y) {
  __shared__ f4 red[2][64];
  int tid = threadIdx.x, lane = tid & 63, w = tid >> 6;
  int bid = blockIdx.x;
  int p = bid >> 2, sub = bid & 3;
  int j = (sub & 1) ? (511 - p) : p;
  int bt = ((sub >> 1) << 1) | (w & 1);
  int kh = w >> 1;
  int nt = (j + 2) >> 1;
  f4 acc = {0.f, 0.f, 0.f, 0.f};
  const short8* Ab = Atab + (size_t)bt * 256 * 64 + lane;
  const short8* Bb = Btab + lane;
  for (int ut = kh; ut < nt; ut += 2) {
    short8 a = Ab[(size_t)ut * 64];
    short8 bf = Bb[(size_t)(j - 2 * ut) * 64];
    acc = __builtin_amdgcn_mfma_f32_16x16x32_bf16(a, bf, acc, 0, 0, 0);
  }
  if (kh == 1) red[w & 1][lane] = acc;
  __syncthreads();
  if (kh == 0) {
    f4 o = red[w & 1][lane];
    float D0 = Dp[0];
    int tt = lane & 15, rq = (lane >> 4) << 2;
#pragma unroll
    for (int r = 0; r < 4; ++r) {
      int row = bt * 16 + rq + r;
      size_t off = (size_t)row * L + j * 16 + tt;
      Y[off] = acc[r] + o[r] + D0 * X[off];
    }
  }
}

extern "C" void kernel_launch(void* const* d_in, const int* in_sizes, int n_in,
                              void* d_out, int out_size, void* d_ws, size_t ws_size,
                              hipStream_t stream) {
  const float* X  = (const float*)d_in[0];
  const float* A  = (const float*)d_in[1];
  const float* Bm = (const float*)d_in[2];
  const float* C  = (const float*)d_in[3];
  const float* D  = (const float*)d_in[4];
  const float* ld = (const float*)d_in[5];
  float* Y = (float*)d_out;

  float* ws = (float*)d_ws;
  float* kv  = ws;
  float* Vtr = ws + 8192;
  float* W   = ws + 73728;
  float* Xi  = ws + 106496;
  float* U2  = ws + 368640;
  float* U3  = ws + 401408;
  float* PB  = ws + 466944;
  unsigned* Atab = (unsigned*)(ws + 3612672);
  unsigned* Btab = (unsigned*)(ws + 3874816);
#define PBUF(i) (PB + (size_t)(i) * (N * N))

  k_p0<<<152, 256, 0, stream>>>(A, C, ld, X, Xi, W, Atab);
  k_lvl64<<<4, 256, 0, stream>>>(A, ld, Xi);
  k_triA<<<32, 256, 0, stream>>>(A, Xi, U2);
  k_triB<<<32, 256, 0, stream>>>(ld, Xi, U2);
  k_triC<<<64, 256, 0, stream>>>(A, Xi, U3);
  k_triD<<<64, 256, 0, stream>>>(ld, Xi, U3);

  k_sqbd<<<152, 256, 0, stream>>>(Xi, PBUF(0), Bm, ld, Vtr);
  k_sqv<<<152, 256, 0, stream>>>(PBUF(0), PBUF(1), Xi, Vtr, 1, 1);
  k_sqv<<<152, 256, 0, stream>>>(PBUF(1), PBUF(2), PBUF(0), Vtr, 2, 0);
  k_sqv<<<152, 256, 0, stream>>>(PBUF(2), PBUF(3), PBUF(1), Vtr, 4, 0);
  k_sqv<<<152, 256, 0, stream>>>(PBUF(3), PBUF(4), PBUF(2), Vtr, 8, 0);
  k_sqv<<<152, 256, 0, stream>>>(PBUF(4), PBUF(5), PBUF(3), Vtr, 16, 0);
  k_sqv<<<152, 256, 0, stream>>>(PBUF(5), PBUF(6), PBUF(4), Vtr, 32, 0);
  k_sqvw<<<168, 256, 0, stream>>>(PBUF(6), PBUF(7), PBUF(5), Vtr, PBUF(6), W);
  k_sqw<<<152, 256, 0, stream>>>(PBUF(7), PBUF(8), PBUF(7), W, 2);
  k_sqw<<<152, 256, 0, stream>>>(PBUF(8), PBUF(9), PBUF(8), W, 4);
  k_sqw<<<152, 256, 0, stream>>>(PBUF(9), PBUF(10), PBUF(9), W, 8);
  k_sqw<<<152, 256, 0, stream>>>(PBUF(10), PBUF(11), PBUF(10), W, 16);
  k_wf<<<16, 256, 0, stream>>>(PBUF(11), W, 32);
  k_kf<<<8, 256, 0, stream>>>(W, Vtr, kv);
  k_bf<<<128, 256, 0, stream>>>(kv, Btab);
  k_convmm<<<1024, 256, 0, stream>>>((const short8*)Atab, (const short8*)Btab, X, D, Y);
#undef PBUF
}

// Round 18
// 416.677 us; speedup vs baseline: 1.3160x; 1.3160x over previous
//
#include <hip/hip_runtime.h>

#define N 512
#define L 8192

#define LOG_MIN -6.907755278982137f
#define LOG_MAX -2.302585092994046f

typedef __attribute__((ext_vector_type(8))) short short8;
typedef __attribute__((ext_vector_type(4))) float f4;
typedef __attribute__((ext_vector_type(4))) unsigned u4;

__device__ __forceinline__ float get_delta(const float* logd) {
  float ld = logd[0];
  ld = fminf(fmaxf(ld, LOG_MIN), LOG_MAX);
  return expf(ld);
}
__device__ __forceinline__ unsigned short f2bf(float x) {
  union { float f; unsigned int u; } c; c.f = x;
  unsigned int u = c.u;
  u += 0x7FFFu + ((u >> 16) & 1u);
  return (unsigned short)(u >> 16);
}
__device__ __forceinline__ unsigned int pack2(unsigned short a, unsigned short b) {
  return (unsigned int)a | ((unsigned int)b << 16);
}

// 16-byte agent-coherent write-through store.
__device__ __forceinline__ void wts4(float* p, f4 v) {
  asm volatile("global_store_dwordx4 %0, %1, off sc0 sc1"
               :: "v"(p), "v"(v) : "memory");
}
__device__ __forceinline__ void wts4u(unsigned* p, u4 v) {
  asm volatile("global_store_dwordx4 %0, %1, off sc0 sc1"
               :: "v"(p), "v"(v) : "memory");
}
__device__ __forceinline__ void ast(float* p, float v) {
  __hip_atomic_store(p, v, __ATOMIC_RELAXED, __HIP_MEMORY_SCOPE_AGENT);
}

#define NB 152u

// Fence-free barrier, counter spread over 8 cache lines.
__device__ __forceinline__ void gsync(unsigned* bar, int p, int b) {
  asm volatile("s_waitcnt vmcnt(0)" ::: "memory");
  __syncthreads();
  if (threadIdx.x == 0) {
    unsigned* base = bar + p * 128;
    __hip_atomic_fetch_add(base + (b & 7) * 16, 1u, __ATOMIC_RELAXED,
                           __HIP_MEMORY_SCOPE_AGENT);
    unsigned s;
    do {
      s = 0;
#pragma unroll
      for (int i = 0; i < 8; ++i)
        s += __hip_atomic_load(base + i * 16, __ATOMIC_RELAXED,
                               __HIP_MEMORY_SCOPE_AGENT);
      if (s < NB) __builtin_amdgcn_s_sleep(2);
    } while (s < NB);
  }
  __syncthreads();
}

// ---------------------------------------------------------------------------
// ws layout (floats). Write-once per address inside k_chain.
//   0        bar   (4096 u32)
//   4096     kvec  (8192)
//   12288    Vtr   (128*512)
//   77824    W     (64*512)
//   110592   Xi    (512*512)
//   372736   U2    (2*128*128)
//   405504   U3    (256*256)
//   471040   PB[12] 12*512*512
//   3616768  Atab  (1MB)   written P0
//   3878912  Btab  (512KB) written P21
// ---------------------------------------------------------------------------

__device__ void diag64(const float* __restrict__ A, float h,
                       float* __restrict__ Xi, int blk, int tid, float* sm) {
  float* Ash = sm;          // [64][65]
  float* xs  = sm + 4160;   // [64][65]
  float* dinv = sm + 8320;  // [64]
  int i0 = blk * 64;
  int r = tid >> 2, c0 = (tid & 3) * 16;
#pragma unroll
  for (int q = 0; q < 16; q += 4) {
    f4 v = *(const f4*)(A + (size_t)(i0 + r) * N + i0 + c0 + q);
    Ash[r * 65 + c0 + q] = v.x; Ash[r * 65 + c0 + q + 1] = v.y;
    Ash[r * 65 + c0 + q + 2] = v.z; Ash[r * 65 + c0 + q + 3] = v.w;
  }
  for (int i = tid; i < 4160; i += 256) xs[i] = 0.f;
  __syncthreads();
  if (tid < 64) dinv[tid] = 1.f / (1.f - h * Ash[tid * 65 + tid]);
  __syncthreads();
  int t = tid >> 2, sub = tid & 3;
  for (int rr = 0; rr < 64; ++rr) {
    if (t <= rr) {
      float s = 0.f;
      for (int k = t + sub; k < rr; k += 4) s += Ash[rr * 65 + k] * xs[k * 65 + t];
      s += __shfl_xor(s, 1, 64);
      s += __shfl_xor(s, 2, 64);
      if (sub == 0)
        xs[rr * 65 + t] = (((rr == t) ? 1.f : 0.f) + h * s) * dinv[rr];
    }
  }
  __syncthreads();
#pragma unroll
  for (int q = 0; q < 16; q += 4) {
    f4 v = {xs[r * 65 + c0 + q], xs[r * 65 + c0 + q + 1],
            xs[r * 65 + c0 + q + 2], xs[r * 65 + c0 + q + 3]};
    wts4(Xi + (size_t)(i0 + r) * N + i0 + c0 + q, v);
  }
}

// Fused level 64->128 for group g: U = A21*X11 (LDS), X21 = h*X22*U.
__device__ void lvl64_fused(const float* __restrict__ A, float* __restrict__ Xi,
                            float h, int g, int tid, float* sm) {
  float* X11s = sm;          // [64][65]
  float* Us   = sm + 4160;   // [64][65]
  int b11 = 128 * g, b22 = 128 * g + 64;
  int r = tid >> 2, c0 = (tid & 3) * 16;
#pragma unroll
  for (int q = 0; q < 16; q += 4) {
    f4 v = *(const f4*)(Xi + (size_t)(b11 + r) * N + b11 + c0 + q);
    X11s[r * 65 + c0 + q] = v.x; X11s[r * 65 + c0 + q + 1] = v.y;
    X11s[r * 65 + c0 + q + 2] = v.z; X11s[r * 65 + c0 + q + 3] = v.w;
  }
  f4 aR[16];
#pragma unroll
  for (int t = 0; t < 16; ++t)
    aR[t] = *(const f4*)(A + (size_t)(b22 + r) * N + b11 + 4 * t);
  __syncthreads();
  float u[16];
#pragma unroll
  for (int j = 0; j < 16; ++j) u[j] = 0.f;
#pragma unroll 4
  for (int k4 = 0; k4 < 16; ++k4) {
    float av[4] = {aR[k4].x, aR[k4].y, aR[k4].z, aR[k4].w};
#pragma unroll
    for (int s = 0; s < 4; ++s) {
      int k = 4 * k4 + s;
      float aa = av[s];
#pragma unroll
      for (int j = 0; j < 16; j += 4) {
        f4 xv = *(const f4*)&X11s[k * 65 + c0 + j];
        u[j] += aa * xv.x; u[j + 1] += aa * xv.y;
        u[j + 2] += aa * xv.z; u[j + 3] += aa * xv.w;
      }
    }
  }
  f4 xR[16];
#pragma unroll
  for (int t = 0; t < 16; ++t)
    xR[t] = *(const f4*)(Xi + (size_t)(b22 + r) * N + b22 + 4 * t);
#pragma unroll
  for (int j = 0; j < 16; ++j) Us[r * 65 + c0 + j] = u[j];
  __syncthreads();
  float x[16];
#pragma unroll
  for (int j = 0; j < 16; ++j) x[j] = 0.f;
#pragma unroll 4
  for (int k4 = 0; k4 < 16; ++k4) {
    float av[4] = {xR[k4].x, xR[k4].y, xR[k4].z, xR[k4].w};
#pragma unroll
    for (int s = 0; s < 4; ++s) {
      int k = 4 * k4 + s;
      float aa = av[s];
#pragma unroll
      for (int j = 0; j < 16; j += 4) {
        f4 xv = *(const f4*)&Us[k * 65 + c0 + j];
        x[j] += aa * xv.x; x[j + 1] += aa * xv.y;
        x[j + 2] += aa * xv.z; x[j + 3] += aa * xv.w;
      }
    }
  }
#pragma unroll
  for (int j = 0; j < 16; j += 4) {
    f4 v = {h * x[j], h * x[j + 1], h * x[j + 2], h * x[j + 3]};
    wts4(&Xi[(size_t)(b22 + r) * N + b11 + c0 + j], v);
  }
}

// All-K-upfront 32x32-tile GEMM; thread owns 1 row x 4 consecutive cols.
template <int NT>
__device__ void gemm32t(const float* __restrict__ A_, int lda,
                        const float* __restrict__ B_, int ldb,
                        float* __restrict__ C_, int ldc,
                        int bi, int bj, float alpha, int tid, float* sm) {
  float* As = sm;          // [32][33]
  float* Bs = sm + 1056;   // [32][36]
  int lr = tid >> 3, lc = (tid & 7) * 4;
  const float* ap = A_ + (size_t)(bi * 32 + lr) * lda + lc;
  const float* bp = B_ + (size_t)lr * ldb + bj * 32 + lc;
  f4 aR[NT], bR[NT];
#pragma unroll
  for (int t = 0; t < NT; ++t) {
    aR[t] = *(const f4*)(ap + 32 * t);
    bR[t] = *(const f4*)(bp + (size_t)(32 * t) * ldb);
  }
  float acc[4] = {0.f, 0.f, 0.f, 0.f};
#pragma unroll
  for (int t = 0; t < NT; ++t) {
    As[lr * 33 + lc] = aR[t].x; As[lr * 33 + lc + 1] = aR[t].y;
    As[lr * 33 + lc + 2] = aR[t].z; As[lr * 33 + lc + 3] = aR[t].w;
    *(f4*)&Bs[lr * 36 + lc] = bR[t];
    __syncthreads();
#pragma unroll
    for (int kk = 0; kk < 32; ++kk) {
      float a = As[lr * 33 + kk];
      f4 bb = *(const f4*)&Bs[kk * 36 + lc];
      acc[0] += a * bb.x; acc[1] += a * bb.y;
      acc[2] += a * bb.z; acc[3] += a * bb.w;
    }
    __syncthreads();
  }
  f4 o = {alpha * acc[0], alpha * acc[1], alpha * acc[2], alpha * acc[3]};
  wts4(&C_[(size_t)(bi * 32 + lr) * ldc + bj * 32 + lc], o);
}

// 32x32-tile lower-tri squaring (first: P := 2P - I on read).
__device__ void sq32(const float* __restrict__ P, float* __restrict__ Q,
                     int bi, int bj, int first, int tid, float* sm) {
  float* As = sm;
  float* Bs = sm + 1056;   // [32][36]
  int lr = tid >> 3, lc = (tid & 7) * 4;
  int nk = bi - bj + 1;
  int kb0 = bj * 32;
  int arow = bi * 32 + lr;
  const float* ap = P + (size_t)arow * N + lc;
  const float* bp = P + bj * 32 + lc;
  f4 aR[16], bR[16];
#pragma unroll
  for (int t = 0; t < 16; ++t) {
    if (t < nk) {
      int kt = kb0 + 32 * t;
      aR[t] = *(const f4*)(ap + kt);
      bR[t] = *(const f4*)(bp + (size_t)(kt + lr) * N);
    }
  }
  float acc[4] = {0.f, 0.f, 0.f, 0.f};
#pragma unroll
  for (int t = 0; t < 16; ++t) {
    if (t < nk) {
      int kb = kb0 + 32 * t;
      float a4[4] = {aR[t].x, aR[t].y, aR[t].z, aR[t].w};
      float b4[4] = {bR[t].x, bR[t].y, bR[t].z, bR[t].w};
      if (first) {
#pragma unroll
        for (int j = 0; j < 4; ++j) {
          a4[j] = 2.f * a4[j] - ((arow == kb + lc + j) ? 1.f : 0.f);
          b4[j] = 2.f * b4[j] - ((kb + lr == bj * 32 + lc + j) ? 1.f : 0.f);
        }
      }
      As[lr * 33 + lc] = a4[0]; As[lr * 33 + lc + 1] = a4[1];
      As[lr * 33 + lc + 2] = a4[2]; As[lr * 33 + lc + 3] = a4[3];
      f4 bv = {b4[0], b4[1], b4[2], b4[3]};
      *(f4*)&Bs[lr * 36 + lc] = bv;
      __syncthreads();
#pragma unroll
      for (int kk = 0; kk < 32; ++kk) {
        float a = As[lr * 33 + kk];
        f4 bb = *(const f4*)&Bs[kk * 36 + lc];
        acc[0] += a * bb.x; acc[1] += a * bb.y;
        acc[2] += a * bb.z; acc[3] += a * bb.w;
      }
      __syncthreads();
    }
  }
  f4 o = {acc[0], acc[1], acc[2], acc[3]};
  wts4(&Q[(size_t)(bi * 32 + lr) * N + bj * 32 + lc], o);
}

// Vtr[base+c][n] = sum_k P[n][k]*Vtr[c][k].
__device__ void vstep_g(const float* __restrict__ P, float* __restrict__ Vtr,
                        int base, int first, int bi, int tid, float* sm) {
  float* As = sm;          // [32][33]
  float* Bs = sm + 1056;   // [32][33]
  int lr = tid >> 3, lc = (tid & 7) * 4;
  int cq = tid >> 3, n4 = (tid & 7) * 4;
  int nk = bi + 1;
  const float* ap = P + (size_t)(bi * 32 + lr) * N + lc;
  f4 aR[16];
#pragma unroll
  for (int t = 0; t < 16; ++t)
    if (t < nk) aR[t] = *(const f4*)(ap + 32 * t);
  int ncj = (base > 32) ? 2 : 1;
  for (int cj = 0; cj < ncj; ++cj) {
    int crow = cj * 32 + lr;
    int cok = (crow < base);
    const float* bp = Vtr + (size_t)crow * N + lc;
    f4 bR[16];
#pragma unroll
    for (int t = 0; t < 16; ++t)
      if (t < nk) bR[t] = cok ? *(const f4*)(bp + 32 * t) : (f4){0.f, 0.f, 0.f, 0.f};
    float acc[4] = {0.f, 0.f, 0.f, 0.f};
#pragma unroll
    for (int t = 0; t < 16; ++t) {
      if (t < nk) {
        int kb = 32 * t;
        float a4[4] = {aR[t].x, aR[t].y, aR[t].z, aR[t].w};
        if (first) {
#pragma unroll
          for (int j = 0; j < 4; ++j)
            a4[j] = 2.f * a4[j] - ((bi * 32 + lr == kb + lc + j) ? 1.f : 0.f);
        }
        As[lr * 33 + lc] = a4[0]; As[lr * 33 + lc + 1] = a4[1];
        As[lr * 33 + lc + 2] = a4[2]; As[lr * 33 + lc + 3] = a4[3];
        Bs[lr * 33 + lc] = bR[t].x; Bs[lr * 33 + lc + 1] = bR[t].y;
        Bs[lr * 33 + lc + 2] = bR[t].z; Bs[lr * 33 + lc + 3] = bR[t].w;
        __syncthreads();
#pragma unroll
        for (int kk = 0; kk < 32; ++kk) {
          float b = Bs[cq * 33 + kk];
          acc[0] += As[(n4 + 0) * 33 + kk] * b;
          acc[1] += As[(n4 + 1) * 33 + kk] * b;
          acc[2] += As[(n4 + 2) * 33 + kk] * b;
          acc[3] += As[(n4 + 3) * 33 + kk] * b;
        }
        __syncthreads();
      }
    }
    int c = cj * 32 + cq;
    if (c < base) {
      f4 o = {acc[0], acc[1], acc[2], acc[3]};
      wts4(&Vtr[(size_t)(base + c) * N + bi * 32 + n4], o);
    }
    if (cj + 1 < ncj) __syncthreads();
  }
}

// W[base+q][c] = sum_k W[q][k]*P[k][c], K from cj*32.
__device__ void wstep_g(const float* __restrict__ P, float* __restrict__ W,
                        int base, int cj, int tid, float* sm) {
  float* As = sm;
  float* Bs = sm + 1056;   // [32][36]
  int lr = tid >> 3, lc = (tid & 7) * 4;
  int kb0 = cj * 32, nk = 16 - cj;
  int qok = (lr < base);
  const float* ap = W + (size_t)lr * N + lc;
  const float* bp = P + cj * 32 + lc;
  f4 aR[16], bR[16];
#pragma unroll
  for (int t = 0; t < 16; ++t) {
    if (t < nk) {
      int kt = kb0 + 32 * t;
      aR[t] = qok ? *(const f4*)(ap + kt) : (f4){0.f, 0.f, 0.f, 0.f};
      bR[t] = *(const f4*)(bp + (size_t)(kt + lr) * N);
    }
  }
  float acc[4] = {0.f, 0.f, 0.f, 0.f};
#pragma unroll
  for (int t = 0; t < 16; ++t) {
    if (t < nk) {
      As[lr * 33 + lc] = aR[t].x; As[lr * 33 + lc + 1] = aR[t].y;
      As[lr * 33 + lc + 2] = aR[t].z; As[lr * 33 + lc + 3] = aR[t].w;
      *(f4*)&Bs[lr * 36 + lc] = bR[t];
      __syncthreads();
#pragma unroll
      for (int kk = 0; kk < 32; ++kk) {
        float a = As[lr * 33 + kk];
        f4 bb = *(const f4*)&Bs[kk * 36 + lc];
        acc[0] += a * bb.x; acc[1] += a * bb.y;
        acc[2] += a * bb.z; acc[3] += a * bb.w;
      }
      __syncthreads();
    }
  }
  if (lr < base) {
    f4 o = {acc[0], acc[1], acc[2], acc[3]};
    wts4(&W[(size_t)(base + lr) * N + cj * 32 + lc], o);
  }
}

// kvec[q][r] = sum_n W[q][n]*Vtr[r][n].
__device__ void kfinal_g(const float* __restrict__ W, const float* __restrict__ Vtr,
                         float* __restrict__ kvec, int bi, int bj, int tid, float* sm) {
  float* As = sm;
  float* Bs = sm + 1056;
  int lr = tid >> 3, lc = (tid & 7) * 4;
  int q = tid >> 3, r4 = (tid & 7) * 4;
  const float* ap = W + (size_t)(bi * 32 + lr) * N + lc;
  const float* bp = Vtr + (size_t)(bj * 32 + lr) * N + lc;
  f4 aR[16], bR[16];
#pragma unroll
  for (int t = 0; t < 16; ++t) {
    aR[t] = *(const f4*)(ap + 32 * t);
    bR[t] = *(const f4*)(bp + 32 * t);
  }
  float acc[4] = {0.f, 0.f, 0.f, 0.f};
#pragma unroll
  for (int t = 0; t < 16; ++t) {
    As[lr * 33 + lc] = aR[t].x; As[lr * 33 + lc + 1] = aR[t].y;
    As[lr * 33 + lc + 2] = aR[t].z; As[lr * 33 + lc + 3] = aR[t].w;
    Bs[lr * 33 + lc] = bR[t].x; Bs[lr * 33 + lc + 1] = bR[t].y;
    Bs[lr * 33 + lc + 2] = bR[t].z; Bs[lr * 33 + lc + 3] = bR[t].w;
    __syncthreads();
#pragma unroll
    for (int kk = 0; kk < 32; ++kk) {
      float a = As[q * 33 + kk];
      acc[0] += a * Bs[(r4 + 0) * 33 + kk];
      acc[1] += a * Bs[(r4 + 1) * 33 + kk];
      acc[2] += a * Bs[(r4 + 2) * 33 + kk];
      acc[3] += a * Bs[(r4 + 3) * 33 + kk];
    }
    __syncthreads();
  }
  f4 o = {acc[0], acc[1], acc[2], acc[3]};
  wts4(&kvec[(size_t)(bi * 32 + q) * 128 + bj * 32 + r4], o);
}

// Vtr[0][n] = delta*(Xi*Bm)[n]: 16 blocks x 32 rows.
__device__ void bd1_body(const float* __restrict__ Xi, const float* __restrict__ Bm,
                         float delta, float* __restrict__ Vtr, int bb, int tid,
                         float* sm) {
  float* bs = sm;
  if (tid < 128) ((f4*)bs)[tid] = ((const f4*)Bm)[tid];
  __syncthreads();
  int w = tid >> 6, lane = tid & 63;
#pragma unroll
  for (int pass = 0; pass < 8; ++pass) {
    int row = bb * 32 + w * 8 + pass;
    const float* Xr = Xi + (size_t)row * N + lane * 8;
    f4 a0 = *(const f4*)Xr;
    f4 a1 = *(const f4*)(Xr + 4);
    const float* bp = bs + lane * 8;
    float acc = a0.x * bp[0] + a0.y * bp[1] + a0.z * bp[2] + a0.w * bp[3]
              + a1.x * bp[4] + a1.y * bp[5] + a1.z * bp[6] + a1.w * bp[7];
    acc += __shfl_xor(acc, 1, 64);
    acc += __shfl_xor(acc, 2, 64);
    acc += __shfl_xor(acc, 4, 64);
    acc += __shfl_xor(acc, 8, 64);
    acc += __shfl_xor(acc, 16, 64);
    acc += __shfl_xor(acc, 32, 64);
    if (lane == 0) ast(&Vtr[row], delta * acc);
  }
}

__device__ __forceinline__ void afrag_unit(const float* __restrict__ X,
                                           unsigned* __restrict__ Atab, int u) {
  int lane = u & 63;
  int f = u >> 6;
  int bt = f >> 8, ut = f & 255;
  int row = bt * 16 + (lane & 15);
  int u0 = ut * 32 + ((lane >> 4) << 3);
  const float* xp = X + (size_t)row * L + u0;
  unsigned short v[8];
#pragma unroll
  for (int e = 0; e < 8; ++e) v[e] = f2bf(xp[e]);
  u4 o = {pack2(v[0], v[1]), pack2(v[2], v[3]), pack2(v[4], v[5]), pack2(v[6], v[7])};
  wts4u(Atab + ((size_t)f * 64 + lane) * 4, o);
}

__device__ __forceinline__ void bfrag_unit(const float* __restrict__ kvec,
                                           unsigned* __restrict__ Btab, int u) {
  int lane = u & 63;
  int si = u >> 6;
  int base = si * 16 + (lane & 15) - ((lane >> 4) << 3);
  unsigned short v[8];
#pragma unroll
  for (int e = 0; e < 8; ++e) {
    int idx = base - e;
    float x = (idx >= 0) ? kvec[idx] : 0.0f;
    v[e] = f2bf(x);
  }
  u4 o = {pack2(v[0], v[1]), pack2(v[2], v[3]), pack2(v[4], v[5]), pack2(v[6], v[7])};
  wts4u(Btab + ((size_t)si * 64 + lane) * 4, o);
}

// --- fused serial chain: 152 blocks, 21 spread-counter barriers -------------
__global__ __launch_bounds__(256) void k_chain(
    const float* __restrict__ A, const float* __restrict__ Bm,
    const float* __restrict__ C, const float* __restrict__ logd,
    const float* __restrict__ X,
    float* __restrict__ Xi, float* __restrict__ U2, float* __restrict__ U3,
    float* __restrict__ PB,
    float* __restrict__ Vtr, float* __restrict__ W, float* __restrict__ kvec,
    unsigned* __restrict__ Atab, unsigned* __restrict__ Btab,
    unsigned* bar) {
  __shared__ float sm[8704];
  int b = blockIdx.x, tid = threadIdx.x;
  float delta = get_delta(logd);
  float h = 0.5f * delta;
#define PBUF(i) (PB + (size_t)(i) * (N * N))
#define GS(p) gsync(bar, (p), b)

  int sbi = 0, srem = b;
  while (srem > sbi) { srem -= (sbi + 1); ++sbi; }
  int sbj = srem;

  // P0: diag inverses + zero strict-upper Xi + W[0]=C + Atab fill
  if (b < 8) {
    diag64(A, h, Xi, b, tid, sm);
  } else if (b < 36) {
    int idx = b - 8, bi = 0, bj = 0, cnt = 0;
    for (int i = 0; i < 8; ++i)
      for (int j = i + 1; j < 8; ++j) { if (cnt == idx) { bi = i; bj = j; } ++cnt; }
    int r = tid >> 2, c0 = (tid & 3) * 16;
    f4 z = {0.f, 0.f, 0.f, 0.f};
#pragma unroll
    for (int q = 0; q < 16; q += 4)
      wts4(Xi + (size_t)(bi * 64 + r) * N + bj * 64 + c0 + q, z);
  } else if (b == 36) {
    for (int i = tid; i < N; i += 256) ast(&W[i], C[i]);
  } else {
    for (int u = (b - 37) * 256 + tid; u < 65536; u += 115 * 256)
      afrag_unit(X, Atab, u);
  }
  GS(0);
  // P1: fused level 64 -> 128 (4 blocks)
  if (b < 4) lvl64_fused(A, Xi, h, b, tid, sm);
  GS(1);
  // P2/P3: level 128 -> 256
  if (b < 32) {
    int g = b >> 4, t = b & 15;
    gemm32t<4>(A + (size_t)(256 * g + 128) * N + 256 * g, N,
               Xi + (size_t)(256 * g) * (N + 1), N,
               U2 + g * 16384, 128, t >> 2, t & 3, 1.0f, tid, sm);
  }
  GS(2);
  if (b < 32) {
    int g = b >> 4, t = b & 15;
    gemm32t<4>(Xi + (size_t)(256 * g + 128) * (N + 1), N, U2 + g * 16384, 128,
               Xi + (size_t)(256 * g + 128) * N + 256 * g, N, t >> 2, t & 3, h, tid, sm);
  }
  GS(3);
  // P4/P5: level 256 -> 512
  if (b < 64)
    gemm32t<8>(A + (size_t)256 * N, N, Xi, N, U3, 256, b >> 3, b & 7, 1.0f, tid, sm);
  GS(4);
  if (b < 64)
    gemm32t<8>(Xi + (size_t)256 * (N + 1), N, U3, 256,
               Xi + (size_t)256 * N, N, b >> 3, b & 7, h, tid, sm);
  GS(5);
  // P6: sq1 (Xi -> Ad^2) || bd1
  if (b < 136) sq32(Xi, PBUF(0), sbi, sbj, 1, tid, sm);
  else bd1_body(Xi, Bm, delta, Vtr, b - 136, tid, sm);
  GS(6);
  // P7..P13: sq2..sq8 || vstep 1,2,4,8,16,32,64
  if (b < 136) sq32(PBUF(0), PBUF(1), sbi, sbj, 0, tid, sm);
  else vstep_g(Xi, Vtr, 1, 1, b - 136, tid, sm);
  GS(7);
  if (b < 136) sq32(PBUF(1), PBUF(2), sbi, sbj, 0, tid, sm);
  else vstep_g(PBUF(0), Vtr, 2, 0, b - 136, tid, sm);
  GS(8);
  if (b < 136) sq32(PBUF(2), PBUF(3), sbi, sbj, 0, tid, sm);
  else vstep_g(PBUF(1), Vtr, 4, 0, b - 136, tid, sm);
  GS(9);
  if (b < 136) sq32(PBUF(3), PBUF(4), sbi, sbj, 0, tid, sm);
  else vstep_g(PBUF(2), Vtr, 8, 0, b - 136, tid, sm);
  GS(10);
  if (b < 136) sq32(PBUF(4), PBUF(5), sbi, sbj, 0, tid, sm);
  else vstep_g(PBUF(3), Vtr, 16, 0, b - 136, tid, sm);
  GS(11);
  if (b < 136) sq32(PBUF(5), PBUF(6), sbi, sbj, 0, tid, sm);
  else vstep_g(PBUF(4), Vtr, 32, 0, b - 136, tid, sm);
  GS(12);
  if (b < 136) sq32(PBUF(6), PBUF(7), sbi, sbj, 0, tid, sm);
  else vstep_g(PBUF(5), Vtr, 64, 0, b - 136, tid, sm);
  GS(13);
  // P14..P17: sq9..sq12 || wstep 1,2,4,8
  if (b < 136) sq32(PBUF(7), PBUF(8), sbi, sbj, 0, tid, sm);
  else wstep_g(PBUF(6), W, 1, b - 136, tid, sm);
  GS(14);
  if (b < 136) sq32(PBUF(8), PBUF(9), sbi, sbj, 0, tid, sm);
  else wstep_g(PBUF(7), W, 2, b - 136, tid, sm);
  GS(15);
  if (b < 136) sq32(PBUF(9), PBUF(10), sbi, sbj, 0, tid, sm);
  else wstep_g(PBUF(8), W, 4, b - 136, tid, sm);
  GS(16);
  if (b < 136) sq32(PBUF(10), PBUF(11), sbi, sbj, 0, tid, sm);
  else wstep_g(PBUF(9), W, 8, b - 136, tid, sm);
  GS(17);
  // P18/P19: wstep 16, 32
  if (b < 16) wstep_g(PBUF(10), W, 16, b, tid, sm);
  GS(18);
  if (b < 16) wstep_g(PBUF(11), W, 32, b, tid, sm);
  GS(19);
  // P20: kvec = W * Vtr^T
  if (b < 8) kfinal_g(W, Vtr, kvec, b >> 2, b & 3, tid, sm);
  GS(20);
  // P21: Toeplitz B-frags
  if (b < 128) bfrag_unit(kvec, Btab, b * 256 + tid);
#undef GS
#undef PBUF
}

// Conv (r5-proven, 39 µs): one 32-wide t-tile per block, 8 waves =
// 4 batch-tiles x 2-way split-K, LDS reduce, register-direct frag loads.
__global__ __launch_bounds__(512) void k_convmm(const short8* __restrict__ Atab,
                                                const short8* __restrict__ Btab,
                                                const float* __restrict__ X,
                                                const float* __restrict__ Dp,
                                                float* __restrict__ Y) {
  int tid = threadIdx.x;
  int lane = tid & 63;
  int w = tid >> 6;
  int bt = w & 3;            // batch tile (rows 16*bt..)
  int kh = w >> 2;           // split-K half
  int blk = blockIdx.x;
  int t0 = blk * 32;
  int nsteps = blk + 1;      // u-tiles of 32
  f4 acc0 = {0.f, 0.f, 0.f, 0.f};
  f4 acc1 = {0.f, 0.f, 0.f, 0.f};
  for (int ut = kh; ut < nsteps; ut += 2) {
    short8 a = Atab[(size_t)(bt * 256 + ut) * 64 + lane];
    int si0 = 2 * (blk - ut);
    short8 b0 = Btab[(size_t)si0 * 64 + lane];
    short8 b1 = Btab[(size_t)(si0 + 1) * 64 + lane];
    acc0 = __builtin_amdgcn_mfma_f32_16x16x32_bf16(a, b0, acc0, 0, 0, 0);
    acc1 = __builtin_amdgcn_mfma_f32_16x16x32_bf16(a, b1, acc1, 0, 0, 0);
  }
  __shared__ float red[4][64][8];
  if (kh == 1) {
#pragma unroll
    for (int r = 0; r < 4; ++r) {
      red[bt][lane][r] = acc0[r];
      red[bt][lane][4 + r] = acc1[r];
    }
  }
  __syncthreads();
  if (kh == 0) {
    float D0 = Dp[0];
#pragma unroll
    for (int r = 0; r < 4; ++r) {
      int bb = bt * 16 + ((lane >> 4) << 2) + r;
      int t = t0 + (lane & 15);
      size_t o0 = (size_t)bb * L + t;
      Y[o0] = acc0[r] + red[bt][lane][r] + D0 * X[o0];
      Y[o0 + 16] = acc1[r] + red[bt][lane][4 + r] + D0 * X[o0 + 16];
    }
  }
}

extern "C" void kernel_launch(void* const* d_in, const int* in_sizes, int n_in,
                              void* d_out, int out_size, void* d_ws, size_t ws_size,
                              hipStream_t stream) {
  const float* X  = (const float*)d_in[0];
  const float* A  = (const float*)d_in[1];
  const float* Bm = (const float*)d_in[2];
  const float* C  = (const float*)d_in[3];
  const float* D  = (const float*)d_in[4];
  const float* ld = (const float*)d_in[5];
  float* Y = (float*)d_out;

  float* ws = (float*)d_ws;
  unsigned* bar = (unsigned*)ws;        // 4096 u32 (spread counters)
  float* kv  = ws + 4096;
  float* Vtr = ws + 12288;
  float* W   = ws + 77824;
  float* Xi  = ws + 110592;
  float* U2  = ws + 372736;
  float* U3  = ws + 405504;
  float* PB  = ws + 471040;
  unsigned* Atab = (unsigned*)(ws + 3616768);
  unsigned* Btab = (unsigned*)(ws + 3878912);

  hipMemsetAsync(bar, 0, 4096 * sizeof(unsigned), stream);
  k_chain<<<152, 256, 0, stream>>>(A, Bm, C, ld, X, Xi, U2, U3, PB, Vtr, W, kv,
                                   Atab, Btab, bar);
  k_convmm<<<256, 512, 0, stream>>>((const short8*)Atab, (const short8*)Btab, X, D, Y);
}